// Round 5
// baseline (192.337 us; speedup 1.0000x reference)
//
#include <hip/hip_runtime.h>

// GaussianKernelRegression == flash attention:
//   s[n,m] = (q_n . t_m - 0.5*|t_m|^2) / std_n^2  (q^2 drops in softmax)
//   out = softmax_m(s) @ source_db
// V7: two INDEPENDENT blocks per CU (round-4 evidence: three pipes at ~36%
// each, dependency-bound at 2 waves/SIMD in one barrier-locked block).
//  - 256-thr blocks = 4 waves = 2 qg x 2 p(m-half). BQ=64, grid 512 = 2/CU.
//    Uncorrelated barriers: block A's stalls filled by block B's MFMAs.
//  - LDS 80KB/block (fits 2/CU): T double-buffered 2x32KB, V single 16KB.
//    Mid-tile counted barrier (vmcnt(8): V+bias waited, 8 T-prefetch ops stay
//    in flight) makes the single V buffer race-free; end-of-tile vmcnt(0)
//    drains T issued ~2000cy earlier (free).
//  - T13 defer-max THR=8: O-rescale only when max grows >8 (log2) => ~never.
//    Partials normalized (O=acc/l) before f16 store (range safety).
// fp16 hi/lo split of T for QK precision (validated r1-r4, absmax .047).

#define N_Q 4096
#define M_DB 16384
#define D_K 256
#define BQ 64
#define BM 32
#define NCHUNK 8
#define NCHE (NCHUNK * 2)    // effective chunks (p-halves independent)
#define MC (M_DB / NCHUNK)   // 2048
#define NTILE (MC / BM)      // 64
#define NCH 8                // k-chunks of 32
#define LOG2E 1.44269504088896f
#define THR 8.0f

typedef _Float16 f16;
typedef _Float16 f16x4v __attribute__((ext_vector_type(4)));
typedef _Float16 f16x8 __attribute__((ext_vector_type(8)));
typedef float f32x4 __attribute__((ext_vector_type(4)));
typedef unsigned short u16;

typedef const __attribute__((address_space(1))) void cg_void;
typedef __attribute__((address_space(3))) void lds_void;

__device__ __forceinline__ void gload16(const void* g, void* s) {
  __builtin_amdgcn_global_load_lds((cg_void*)g, (lds_void*)s, 16, 0, 0);
}

// ---------- prep: Q fragment blobs. blob qt: slot=c*64+l, lane l elem e -> Q[qt*16+(l&15)][c*32+((l>>4)&3)*8+e]
__global__ void k_prep_q(const float* __restrict__ q, u16* __restrict__ qpk) {
  int qt = blockIdx.x;
  int t = threadIdx.x;
#pragma unroll
  for (int i = 0; i < 2; i++) {
    int slot = t + 256 * i;
    int c = slot >> 6, l = slot & 63;
    int row = qt * 16 + (l & 15);
    int k0 = c * 32 + ((l >> 4) & 3) * 8;
    const float* src = q + (size_t)row * D_K + k0;
    f16x8 o;
#pragma unroll
    for (int e = 0; e < 8; e++) o[e] = (f16)src[e];
    *(f16x8*)(qpk + (size_t)qt * 4096 + slot * 8) = o;
  }
}

// ---------- prep: 0.5 * row-sum-sq of target_db
__global__ void k_prep_tq(const float* __restrict__ tdb, float* __restrict__ tq) {
  int t = threadIdx.x;
  int row = blockIdx.x * 8 + (t >> 5);
  int ln = t & 31;
  float s = 0.f;
#pragma unroll
  for (int i = 0; i < 8; i++) { float x = tdb[(size_t)row * D_K + ln + 32 * i]; s += x * x; }
#pragma unroll
  for (int off = 16; off >= 1; off >>= 1) s += __shfl_xor(s, off);
  if (ln == 0) tq[row] = 0.5f * s;
}

// ---------- prep: T fragment blobs (hi/lo fp16 split). chunk = p*1024 + c*128 + hl*64 + l
__global__ void k_prep_t(const float* __restrict__ tdb, u16* __restrict__ pkT) {
  int ti = blockIdx.x;
  int t = threadIdx.x;
#pragma unroll
  for (int i = 0; i < 8; i++) {
    int ck = t + 256 * i;
    int l = ck & 63, hl = (ck >> 6) & 1, c = (ck >> 7) & 7, p = (ck >> 10) & 1;
    int row = ti * 32 + p * 16 + (l & 15);
    int k0 = c * 32 + ((l >> 4) & 3) * 8;
    const float* src = tdb + (size_t)row * D_K + k0;
    f16x8 o;
#pragma unroll
    for (int e = 0; e < 8; e++) {
      float v = src[e];
      f16 h = (f16)v;
      o[e] = hl ? (f16)(v - (float)h) : h;
    }
    *(f16x8*)(pkT + (size_t)ti * 16384 + ck * 8) = o;   // 32KB per tile
  }
}

// ---------- prep: V^T paired A-frag blobs (16x16x16). slot = p*512 + c*64 + l:
// lane l elem e -> V[ti*32 + p*16 + ((l>>4)&3)*4 + (e&3)][c*32 + (e>>2)*16 + (l&15)]
__global__ void k_prep_v(const float* __restrict__ src, u16* __restrict__ pkV) {
  int ti = blockIdx.x;   // M_DB/32 tiles
  int t = threadIdx.x;   // 256
#pragma unroll
  for (int i = 0; i < 4; i++) {
    int slot = t + 256 * i;
    int l = slot & 63, c = (slot >> 6) & 7, p = slot >> 9;
    int mbase = ti * 32 + p * 16 + ((l >> 4) & 3) * 4;
    int dbase = c * 32 + (l & 15);
    f16x8 o;
#pragma unroll
    for (int e = 0; e < 8; e++)
      o[e] = (f16)src[(size_t)(mbase + (e & 3)) * D_K + dbase + (e >> 2) * 16];
    *(f16x8*)(pkV + (size_t)ti * 8192 + slot * 8) = o;   // 16KB per tile
  }
}

// ---------- main flash kernel ----------
__launch_bounds__(256, 2)
__global__ void k_main(const u16* __restrict__ qpk, const u16* __restrict__ pkT,
                       const u16* __restrict__ pkV, const float* __restrict__ tq,
                       const float* __restrict__ stdv,
                       u16* __restrict__ pO, float* __restrict__ pm, float* __restrict__ pl)
{
  __shared__ __align__(16) char su[81920];   // [T0 32K][T1 32K][V 16K] = 80KB

  const int bid = blockIdx.x, chunk = bid & 7, qblk = bid >> 3;
  const int tid = threadIdx.x;
  const int w = tid >> 6, l = tid & 63;
  const int qg = w >> 1, p = w & 1;
  const int lq = l & 15, mg = (l >> 4) & 3;

  float is2l[2];
#pragma unroll
  for (int f = 0; f < 2; f++) {
    float sd = stdv[qblk * BQ + qg * 32 + f * 16 + lq];
    is2l[f] = LOG2E / (sd * sd);
  }

  // 2 Q fragment sets in registers (64 VGPRs)
  f16x8 qf[2][NCH];
#pragma unroll
  for (int f = 0; f < 2; f++) {
    const u16* qb = qpk + (size_t)(qblk * 4 + qg * 2 + f) * 4096 + l * 8;
#pragma unroll
    for (int c = 0; c < NCH; c++) qf[f][c] = *(const f16x8*)(qb + c * 512);
  }

  f32x4 acc[2][16];   // O^T partials over this wave's own m-half (full d)
#pragma unroll
  for (int f = 0; f < 2; f++)
#pragma unroll
    for (int dc = 0; dc < 16; dc++) acc[f][dc] = (f32x4){0.f, 0.f, 0.f, 0.f};
  float mrun[2] = {-3.0e38f, -3.0e38f}, lrun[2] = {0.f, 0.f};

  const size_t tbase = (size_t)chunk * NTILE;

  auto stageT = [&](int t, int buf) {   // 8 x gload16 (32KB)
    const char* gT = (const char*)pkT + (tbase + t) * 32768;
    char* sb = &su[0] + buf * 32768;
#pragma unroll
    for (int i = 0; i < 8; i++) gload16(gT + i * 4096 + tid * 16, sb + i * 4096 + w * 1024);
  };
  auto stageV = [&](int t) {            // 4 x gload16 (16KB)
    const char* gV = (const char*)pkV + (tbase + t) * 16384;
    char* sb = &su[0] + 65536;
#pragma unroll
    for (int i = 0; i < 4; i++) gload16(gV + i * 4096 + tid * 16, sb + i * 4096 + w * 1024);
  };

  // prologue: T(0) staged and visible
  stageT(0, 0);
  asm volatile("s_waitcnt vmcnt(0)" ::: "memory");
  __builtin_amdgcn_s_barrier();

  for (int t = 0; t < NTILE; ++t) {
    const int cur = t & 1, nxt = cur ^ 1;
    const bool hasNext = (t + 1 < NTILE);

    // 1. stage V(t) (single buffer; prior-tile readers drained by end barrier)
    stageV(t);
    // 2. per-lane t_sq bias (compiler-tracked load)
    const f32x4 t4 = *(const f32x4*)(tq + chunk * MC + t * BM + p * 16 + mg * 4);
    // 3. prefetch T(t+1) (8 ops, stay in flight across mid-tile barrier)
    if (hasNext) stageT(t + 1, nxt);

    // 4. QK^T swapped: A=T (own m-half 16), B=Q regs -> D[m][q]; 4 indep chains
    f32x4 s0H = {0.f,0.f,0.f,0.f}, s0L = {0.f,0.f,0.f,0.f};
    f32x4 s1H = {0.f,0.f,0.f,0.f}, s1L = {0.f,0.f,0.f,0.f};
    const char* tb = &su[0] + cur * 32768 + p * 16384 + l * 16;
    __builtin_amdgcn_s_setprio(1);
#pragma unroll
    for (int c = 0; c < NCH; c++) {
      f16x8 aH = *(const f16x8*)(tb + c * 2048);
      f16x8 aL = *(const f16x8*)(tb + c * 2048 + 1024);
      s0H = __builtin_amdgcn_mfma_f32_16x16x32_f16(aH, qf[0][c], s0H, 0, 0, 0);
      s1H = __builtin_amdgcn_mfma_f32_16x16x32_f16(aH, qf[1][c], s1H, 0, 0, 0);
      s0L = __builtin_amdgcn_mfma_f32_16x16x32_f16(aL, qf[0][c], s0L, 0, 0, 0);
      s1L = __builtin_amdgcn_mfma_f32_16x16x32_f16(aL, qf[1][c], s1L, 0, 0, 0);
    }
    __builtin_amdgcn_s_setprio(0);

    float l20[4], l21[4];
#pragma unroll
    for (int r = 0; r < 4; r++) {
      l20[r] = (s0H[r] + s0L[r] - t4[r]) * is2l[0];
      l21[r] = (s1H[r] + s1L[r] - t4[r]) * is2l[1];
    }
    float px0 = fmaxf(fmaxf(l20[0], l20[1]), fmaxf(l20[2], l20[3]));
    float px1 = fmaxf(fmaxf(l21[0], l21[1]), fmaxf(l21[2], l21[3]));
    px0 = fmaxf(px0, __shfl_xor(px0, 16)); px0 = fmaxf(px0, __shfl_xor(px0, 32));
    px1 = fmaxf(px1, __shfl_xor(px1, 16)); px1 = fmaxf(px1, __shfl_xor(px1, 32));

    // T13 defer-max: rescale only when max grew by > THR (log2) -> ~never
    if (__any((px0 > mrun[0] + THR) | (px1 > mrun[1] + THR))) {
      const float mnew0 = fmaxf(mrun[0], px0);
      const float mnew1 = fmaxf(mrun[1], px1);
      const float cl0 = exp2f(mrun[0] - mnew0);
      const float cl1 = exp2f(mrun[1] - mnew1);
      mrun[0] = mnew0; mrun[1] = mnew1;
      lrun[0] *= cl0;  lrun[1] *= cl1;
#pragma unroll
      for (int dc = 0; dc < 16; dc++) {
#pragma unroll
        for (int r = 0; r < 4; r++) { acc[0][dc][r] *= cl0; acc[1][dc][r] *= cl1; }
      }
    }
    float pr0[4], pr1[4], ls0 = 0.f, ls1 = 0.f;
#pragma unroll
    for (int r = 0; r < 4; r++) {
      pr0[r] = exp2f(l20[r] - mrun[0]); ls0 += pr0[r];
      pr1[r] = exp2f(l21[r] - mrun[1]); ls1 += pr1[r];
    }
    ls0 += __shfl_xor(ls0, 16); ls0 += __shfl_xor(ls0, 32);
    ls1 += __shfl_xor(ls1, 16); ls1 += __shfl_xor(ls1, 32);
    lrun[0] += ls0; lrun[1] += ls1;

    f16x4v pf0, pf1;   // P as B-operand frags straight from regs (K=16 own m-half)
#pragma unroll
    for (int r = 0; r < 4; r++) { pf0[r] = (f16)pr0[r]; pf1[r] = (f16)pr1[r]; }

    // 5. mid-tile counted barrier: own V+t4 waited (T(t+1) 8 ops stay in
    //    flight); barrier => ALL waves' V writes complete & visible.
    if (hasNext) asm volatile("s_waitcnt vmcnt(8)" ::: "memory");
    else         asm volatile("s_waitcnt vmcnt(0)" ::: "memory");
    __builtin_amdgcn_s_barrier();

    // 6. PV swapped: acc[f][dc] += V^T_frag(dc) * pf[f]
    const char* vb = &su[0] + 65536 + p * 8192 + l * 16;
    __builtin_amdgcn_s_setprio(1);
#pragma unroll
    for (int c = 0; c < 8; c++) {
      f16x8 vv = *(const f16x8*)(vb + c * 1024);
      f16x4v a0 = __builtin_shufflevector(vv, vv, 0, 1, 2, 3);
      f16x4v a1 = __builtin_shufflevector(vv, vv, 4, 5, 6, 7);
      acc[0][2 * c]     = __builtin_amdgcn_mfma_f32_16x16x16f16(a0, pf0, acc[0][2 * c], 0, 0, 0);
      acc[1][2 * c]     = __builtin_amdgcn_mfma_f32_16x16x16f16(a0, pf1, acc[1][2 * c], 0, 0, 0);
      acc[0][2 * c + 1] = __builtin_amdgcn_mfma_f32_16x16x16f16(a1, pf0, acc[0][2 * c + 1], 0, 0, 0);
      acc[1][2 * c + 1] = __builtin_amdgcn_mfma_f32_16x16x16f16(a1, pf1, acc[1][2 * c + 1], 0, 0, 0);
    }
    __builtin_amdgcn_s_setprio(0);

    // 7. end-of-tile: T(t+1) (issued ~2000cy ago) drained; all PV reads retired
    if (hasNext) {
      asm volatile("s_waitcnt vmcnt(0)" ::: "memory");
      __builtin_amdgcn_s_barrier();
    }
  }

  // ---- epilogue: normalize (O = acc/l), store own-chunk partials (f16) ----
  const int ce = chunk * 2 + p;
#pragma unroll
  for (int f = 0; f < 2; f++) {
    const float inv = 1.0f / lrun[f];
    const int row = qblk * BQ + qg * 32 + f * 16 + lq;
#pragma unroll
    for (int dc = 0; dc < 16; dc++) {
      f16x4v o4;
#pragma unroll
      for (int r = 0; r < 4; r++) o4[r] = (f16)(acc[f][dc][r] * inv);
      *(f16x4v*)(pO + ((size_t)ce * N_Q + row) * D_K + dc * 16 + mg * 4) = o4;
    }
    if (mg == 0) {
      pm[(size_t)ce * N_Q + row] = mrun[f];
      pl[(size_t)ce * N_Q + row] = lrun[f];
    }
  }
}

// ---------- combine chunk partials (O-hat = normalized partials) ----------
__global__ void k_combine(const u16* __restrict__ pO, const float* __restrict__ pm,
                          const float* __restrict__ pl, float* __restrict__ out)
{
  int n = blockIdx.x, d = threadIdx.x;
  float M = -3.0e38f;
#pragma unroll
  for (int c = 0; c < NCHE; c++) M = fmaxf(M, pm[(size_t)c * N_Q + n]);
  float den = 0.f, num = 0.f;
#pragma unroll
  for (int c = 0; c < NCHE; c++) {
    float wl = exp2f(pm[(size_t)c * N_Q + n] - M) * pl[(size_t)c * N_Q + n];
    den += wl;
    float v = (float)(*(const f16*)(pO + ((size_t)c * N_Q + n) * D_K + d));
    num += wl * v;
  }
  out[(size_t)n * D_K + d] = num / den;
}

extern "C" void kernel_launch(void* const* d_in, const int* in_sizes, int n_in,
                              void* d_out, int out_size, void* d_ws, size_t ws_size,
                              hipStream_t stream)
{
  const float* q    = (const float*)d_in[0];
  const float* stdv = (const float*)d_in[1];
  const float* src  = (const float*)d_in[2];   // source_db (V)
  const float* tdb  = (const float*)d_in[3];   // target_db (T)
  float* out = (float*)d_out;

  char* wsp = (char*)d_ws;
  u16* qpk = (u16*)wsp;   wsp += (size_t)N_Q * D_K * 2;            // 2 MB
  u16* pkT = (u16*)wsp;   wsp += (size_t)M_DB * D_K * 2 * 2;       // 16.8 MB (hi+lo)
  u16* pkV = (u16*)wsp;   wsp += (size_t)M_DB * D_K * 2;           // 8.4 MB
  float* tq = (float*)wsp; wsp += (size_t)M_DB * 4;                // 64 KB
  u16* pO = (u16*)wsp;    wsp += (size_t)NCHE * N_Q * D_K * 2;     // 33.5 MB (f16)
  float* pm = (float*)wsp; wsp += (size_t)NCHE * N_Q * 4;
  float* pl = (float*)wsp; wsp += (size_t)NCHE * N_Q * 4;

  hipLaunchKernelGGL(k_prep_q,  dim3(N_Q / 16), dim3(256), 0, stream, q, qpk);
  hipLaunchKernelGGL(k_prep_tq, dim3(M_DB / 8), dim3(256), 0, stream, tdb, tq);
  hipLaunchKernelGGL(k_prep_t,  dim3(M_DB / 32), dim3(256), 0, stream, tdb, pkT);
  hipLaunchKernelGGL(k_prep_v,  dim3(M_DB / 32), dim3(256), 0, stream, src, pkV);
  hipLaunchKernelGGL(k_main,    dim3((N_Q / BQ) * NCHUNK), dim3(256), 0, stream,
                     qpk, pkT, pkV, tq, stdv, pO, pm, pl);
  hipLaunchKernelGGL(k_combine, dim3(N_Q), dim3(256), 0, stream, pO, pm, pl, out);
}